// Round 3
// baseline (534.702 us; speedup 1.0000x reference)
//
#include <hip/hip_runtime.h>
#include <hip/hip_bf16.h>
#include <stdint.h>

#define TOKENS 2048
#define HDIM 1024
#define FDIM 3584
#define NEXP 8
#define BK 32

typedef __attribute__((ext_vector_type(8))) short short8;
typedef __attribute__((ext_vector_type(4))) float floatx4;

#define AS1 __attribute__((address_space(1)))
#define AS3 __attribute__((address_space(3)))

__device__ __forceinline__ void glds16(const void* g, void* l) {
  __builtin_amdgcn_global_load_lds((const AS1 void*)g, (AS3 void*)l, 16, 0, 0);
}

__device__ __forceinline__ unsigned short f2bf(float f) {
  union { float f; unsigned int u; } c; c.f = f;
  unsigned int u = c.u;
  u += 0x7fffu + ((u >> 16) & 1u);
  return (unsigned short)(u >> 16);
}

__device__ __forceinline__ unsigned int pk2bf(float a, float b) {
  __hip_bfloat162 h = __float22bfloat162_rn(make_float2(a, b));
  union { __hip_bfloat162 h; unsigned int u; } c; c.h = h;
  return c.u;
}

// ---------------- gating (no atomics) ----------------
__global__ void gate_kernel(const float* __restrict__ x,
                            const float* __restrict__ gw,
                            int* __restrict__ top_e,
                            float* __restrict__ top_w) {
  int wv = threadIdx.x >> 6;
  int lane = threadIdx.x & 63;
  int t = blockIdx.x * 4 + wv;
  if (t >= TOKENS) return;
  float p[NEXP];
#pragma unroll
  for (int e = 0; e < NEXP; e++) p[e] = 0.f;
  const float* xr = x + (size_t)t * HDIM;
  for (int h = lane; h < HDIM; h += 64) {
    float xv = xr[h];
    const float4* g4 = (const float4*)(gw + (size_t)h * NEXP);
    float4 a = g4[0], b = g4[1];
    p[0] += xv * a.x; p[1] += xv * a.y; p[2] += xv * a.z; p[3] += xv * a.w;
    p[4] += xv * b.x; p[5] += xv * b.y; p[6] += xv * b.z; p[7] += xv * b.w;
  }
#pragma unroll
  for (int e = 0; e < NEXP; e++) {
#pragma unroll
    for (int off = 32; off > 0; off >>= 1) p[e] += __shfl_xor(p[e], off, 64);
  }
  if (lane == 0) {
    int i0 = 0;
    for (int e = 1; e < NEXP; e++) if (p[e] > p[i0]) i0 = e;
    int i1 = (i0 == 0) ? 1 : 0;
    for (int e = 0; e < NEXP; e++) if (e != i0 && p[e] > p[i1]) i1 = e;
    float l0 = p[i0], l1 = p[i1];
    float e1 = __expf(l1 - l0);
    float s = 1.f + e1;
    top_e[t * 2] = i0; top_e[t * 2 + 1] = i1;
    top_w[t * 2] = 1.f / s; top_w[t * 2 + 1] = e1 / s;
  }
}

// ---------------- fused count + offsets + scatter (single block, LDS atomics only) ----------------
__global__ void route_kernel(const int* __restrict__ top_e,
                             int* __restrict__ count,
                             int* __restrict__ offs,
                             int* __restrict__ tok_of,
                             int* __restrict__ slot_of) {
  __shared__ int hist[NEXP];
  __shared__ int cur[NEXP];
  int tid = threadIdx.x;  // 1024 threads, 4 entries each
  if (tid < NEXP) hist[tid] = 0;
  __syncthreads();
  int e[4];
#pragma unroll
  for (int j = 0; j < 4; j++) {
    int i = tid * 4 + j;
    e[j] = top_e[i];
    atomicAdd(&hist[e[j]], 1);
  }
  __syncthreads();
  if (tid == 0) {
    int o = 0;
    for (int k = 0; k < NEXP; k++) {
      offs[k] = o; cur[k] = o; count[k] = hist[k]; o += hist[k];
    }
  }
  __syncthreads();
#pragma unroll
  for (int j = 0; j < 4; j++) {
    int i = tid * 4 + j;
    int g = atomicAdd(&cur[e[j]], 1);
    tok_of[g] = i >> 1;
    slot_of[i] = g;
  }
}

// ---------------- conversions ----------------
__global__ void xconv_kernel(const float* __restrict__ x,
                             unsigned short* __restrict__ xbf) {
  int i = (blockIdx.x * blockDim.x + threadIdx.x) * 4;
  float4 v = *(const float4*)(x + i);
  uint2 pk;
  pk.x = pk2bf(v.x, v.y);
  pk.y = pk2bf(v.z, v.w);
  *(uint2*)(xbf + i) = pk;
}

// weight conversion: wave-blocked contiguous loads (lane i -> base + i*16B),
// grid-stride x4. blockIdx.y selects tensor.
#define WCONV_N (29360128ull)           // 8*3584*1024 floats per tensor
#define WCONV_BLK 3584                  // 4 grid-stride iters per block
__global__ void wconv_kernel(const float* __restrict__ w1,
                             const float* __restrict__ w3,
                             const float* __restrict__ w2,
                             unsigned short* __restrict__ b1,
                             unsigned short* __restrict__ b3,
                             unsigned short* __restrict__ b2) {
  int z = blockIdx.y;
  const float* src = (z == 0) ? w1 : (z == 1) ? w3 : w2;
  unsigned short* dst = (z == 0) ? b1 : (z == 1) ? b3 : b2;
  int t4 = threadIdx.x * 4;
  for (size_t base = (size_t)blockIdx.x * 2048; base < WCONV_N;
       base += (size_t)WCONV_BLK * 2048) {
    float4 a = *(const float4*)(src + base + t4);           // lanes contiguous: 1KB/instr
    float4 b = *(const float4*)(src + base + 1024 + t4);
    uint2 pa, pb;
    pa.x = pk2bf(a.x, a.y); pa.y = pk2bf(a.z, a.w);
    pb.x = pk2bf(b.x, b.y); pb.y = pk2bf(b.z, b.w);
    *(uint2*)(dst + base + t4) = pa;
    *(uint2*)(dst + base + 1024 + t4) = pb;
  }
}

// ---------------- GEMM1: act = silu(X w1^T) * (X w3^T), 128x64 tile, all-bf16 ----------------
// 2-phase pipeline: double-buffered LDS, one barrier per K-step, next-tile
// glds issued before current-tile ds_read+MFMA (T3 minimum-2-phase recipe).
// chunk-swizzle s = q ^ ((r>>1)&3) -> 2-way (free)
#define G1_BM 128
#define G1_BF 64

__global__ __launch_bounds__(256, 3)
void gemm1_kernel(const unsigned short* __restrict__ xbf,
                  const unsigned short* __restrict__ w1b,
                  const unsigned short* __restrict__ w3b,
                  const int* __restrict__ count,
                  const int* __restrict__ offs,
                  const int* __restrict__ tok_of,
                  unsigned short* __restrict__ act) {
  int e = blockIdx.z;
  int cnt = count[e];
  int m0 = blockIdx.y * G1_BM;
  if (m0 >= cnt) return;
  int f0 = blockIdx.x * G1_BF;
  int off_e = offs[e];

  __shared__ __align__(16) unsigned short sA[2 * G1_BM * 32];   // 2 x 8 KB
  __shared__ __align__(16) unsigned short sB1[2 * G1_BF * 32];  // 2 x 4 KB
  __shared__ __align__(16) unsigned short sB3[2 * G1_BF * 32];  // 2 x 4 KB

  int tid = threadIdx.x;
  int lane = tid & 63, wv = tid >> 6;

  // A staging: 512 chunks -> 2 per thread
  const unsigned short* ag[2];
  char* alb[2];
#pragma unroll
  for (int p = 0; p < 2; p++) {
    int c = tid + p * 256;
    int row = c >> 2, slot = c & 3;
    int gch = slot ^ ((row >> 1) & 3);
    int r = m0 + row;
    int tok = tok_of[off_e + (r < cnt ? r : 0)];
    ag[p] = xbf + (size_t)tok * HDIM + gch * 8;
    alb[p] = (char*)sA + (wv * 64 + p * 256) * 16;
  }
  // B staging: 256 chunks each -> 1 per thread
  const unsigned short *b1g, *b3g;
  char *b1l, *b3l;
  {
    int row = tid >> 2, slot = tid & 3;
    int gch = slot ^ ((row >> 1) & 3);
    size_t wrow = (size_t)e * FDIM + f0 + row;
    b1g = w1b + wrow * HDIM + gch * 8;
    b3g = w3b + wrow * HDIM + gch * 8;
    b1l = (char*)sB1 + (wv * 64) * 16;
    b3l = (char*)sB3 + (wv * 64) * 16;
  }

  int lrow = lane & 15, quad = lane >> 4;
  int wm = wv >> 1, wn = wv & 1;

  floatx4 acc1[4][2], acc3[4][2];
#pragma unroll
  for (int i = 0; i < 4; i++)
#pragma unroll
    for (int j = 0; j < 2; j++) {
      acc1[i][j] = (floatx4){0.f, 0.f, 0.f, 0.f};
      acc3[i][j] = (floatx4){0.f, 0.f, 0.f, 0.f};
    }

  const int NT = HDIM / BK;  // 32

  // prologue: stage tile 0 into buf 0
#pragma unroll
  for (int p = 0; p < 2; p++) glds16(ag[p], alb[p]);
  glds16(b1g, b1l);
  glds16(b3g, b3l);
  __syncthreads();   // vmcnt(0) drain + barrier

  int cur = 0;
  for (int t = 0; t < NT; t++) {
    // issue next-tile staging into the other buffer (overlaps with MFMA below)
    if (t + 1 < NT) {
      int k = (t + 1) * BK;
      int nb = cur ^ 1;
#pragma unroll
      for (int p = 0; p < 2; p++) glds16(ag[p] + k, alb[p] + nb * 8192);
      glds16(b1g + k, b1l + nb * 4096);
      glds16(b3g + k, b3l + nb * 4096);
    }

    const unsigned short* sAc = sA + cur * (G1_BM * 32);
    const unsigned short* sB1c = sB1 + cur * (G1_BF * 32);
    const unsigned short* sB3c = sB3 + cur * (G1_BF * 32);

    short8 af[4], b1f[2], b3f[2];
#pragma unroll
    for (int ms = 0; ms < 4; ms++) {
      int r = wm * 64 + ms * 16 + lrow;
      int sl = quad ^ ((r >> 1) & 3);
      af[ms] = *(const short8*)(sAc + r * 32 + sl * 8);
    }
#pragma unroll
    for (int ns = 0; ns < 2; ns++) {
      int r = wn * 32 + ns * 16 + lrow;
      int sl = quad ^ ((r >> 1) & 3);
      b1f[ns] = *(const short8*)(sB1c + r * 32 + sl * 8);
      b3f[ns] = *(const short8*)(sB3c + r * 32 + sl * 8);
    }
#pragma unroll
    for (int ms = 0; ms < 4; ms++)
#pragma unroll
      for (int ns = 0; ns < 2; ns++) {
        acc1[ms][ns] = __builtin_amdgcn_mfma_f32_16x16x32_bf16(af[ms], b1f[ns], acc1[ms][ns], 0, 0, 0);
        acc3[ms][ns] = __builtin_amdgcn_mfma_f32_16x16x32_bf16(af[ms], b3f[ns], acc3[ms][ns], 0, 0, 0);
      }

    __syncthreads();   // drains the staging issued above; next buffer ready
    cur ^= 1;
  }

#pragma unroll
  for (int ms = 0; ms < 4; ms++) {
#pragma unroll
    for (int reg = 0; reg < 4; reg++) {
      int slot = m0 + wm * 64 + ms * 16 + quad * 4 + reg;
      if (slot < cnt) {
        unsigned short* ar = act + (size_t)(off_e + slot) * FDIM + f0 + wn * 32;
#pragma unroll
        for (int ns = 0; ns < 2; ns++) {
          float h = acc1[ms][ns][reg];
          float g = acc3[ms][ns][reg];
          float a = h / (1.f + __expf(-h)) * g;
          ar[ns * 16 + lrow] = f2bf(a);
        }
      }
    }
  }
}

// ---------------- GEMM2: partial[sk] = act w2^T over K-slice, 128x128 tile, all-bf16 ----------------
#define G2_BM 128
#define G2_BN 128
#define SPLITK 2
#define G2_KS (FDIM / SPLITK)   // 1792

__global__ __launch_bounds__(256, 3)
void gemm2_kernel(const unsigned short* __restrict__ act,
                  const unsigned short* __restrict__ w2b,
                  const int* __restrict__ count,
                  const int* __restrict__ offs,
                  float* __restrict__ part) {
  int zz = blockIdx.z;
  int e = zz & 7, sk = zz >> 3;
  int cnt = count[e];
  int m0 = blockIdx.y * G2_BM;
  if (m0 >= cnt) return;
  int h0 = blockIdx.x * G2_BN;
  int off_e = offs[e];
  int kb = sk * G2_KS;

  __shared__ __align__(16) unsigned short sA[2 * G2_BM * 32];  // 2 x 8 KB
  __shared__ __align__(16) unsigned short sB[2 * G2_BN * 32];  // 2 x 8 KB

  int tid = threadIdx.x;
  int lane = tid & 63, wv = tid >> 6;

  const unsigned short* ag[2];
  char* alb[2];
#pragma unroll
  for (int p = 0; p < 2; p++) {
    int c = tid + p * 256;
    int row = c >> 2, slot = c & 3;
    int gch = slot ^ ((row >> 1) & 3);
    int r = m0 + row;
    int rr = (r < cnt ? r : 0);
    ag[p] = act + (size_t)(off_e + rr) * FDIM + kb + gch * 8;
    alb[p] = (char*)sA + (wv * 64 + p * 256) * 16;
  }
  const unsigned short* bg[2];
  char* blb[2];
#pragma unroll
  for (int p = 0; p < 2; p++) {
    int c = tid + p * 256;
    int row = c >> 2, slot = c & 3;
    int gch = slot ^ ((row >> 1) & 3);
    bg[p] = w2b + ((size_t)e * HDIM + h0 + row) * FDIM + kb + gch * 8;
    blb[p] = (char*)sB + (wv * 64 + p * 256) * 16;
  }

  int lrow = lane & 15, quad = lane >> 4;
  int wm = wv >> 1, wn = wv & 1;

  floatx4 acc[4][4];
#pragma unroll
  for (int i = 0; i < 4; i++)
#pragma unroll
    for (int j = 0; j < 4; j++) acc[i][j] = (floatx4){0.f, 0.f, 0.f, 0.f};

  const int NT = G2_KS / BK;  // 56

  // prologue
#pragma unroll
  for (int p = 0; p < 2; p++) { glds16(ag[p], alb[p]); glds16(bg[p], blb[p]); }
  __syncthreads();

  int cur = 0;
  for (int t = 0; t < NT; t++) {
    if (t + 1 < NT) {
      int k = (t + 1) * BK;
      int nb = cur ^ 1;
#pragma unroll
      for (int p = 0; p < 2; p++) {
        glds16(ag[p] + k, alb[p] + nb * 8192);
        glds16(bg[p] + k, blb[p] + nb * 8192);
      }
    }

    const unsigned short* sAc = sA + cur * (G2_BM * 32);
    const unsigned short* sBc = sB + cur * (G2_BN * 32);

    short8 af[4], bf[4];
#pragma unroll
    for (int ms = 0; ms < 4; ms++) {
      int r = wm * 64 + ms * 16 + lrow;
      int sl = quad ^ ((r >> 1) & 3);
      af[ms] = *(const short8*)(sAc + r * 32 + sl * 8);
    }
#pragma unroll
    for (int ns = 0; ns < 4; ns++) {
      int r = wn * 64 + ns * 16 + lrow;
      int sl = quad ^ ((r >> 1) & 3);
      bf[ns] = *(const short8*)(sBc + r * 32 + sl * 8);
    }
#pragma unroll
    for (int ms = 0; ms < 4; ms++)
#pragma unroll
      for (int ns = 0; ns < 4; ns++)
        acc[ms][ns] = __builtin_amdgcn_mfma_f32_16x16x32_bf16(af[ms], bf[ns], acc[ms][ns], 0, 0, 0);

    __syncthreads();
    cur ^= 1;
  }

#pragma unroll
  for (int ms = 0; ms < 4; ms++) {
#pragma unroll
    for (int reg = 0; reg < 4; reg++) {
      int slot = m0 + wm * 64 + ms * 16 + quad * 4 + reg;
      if (slot < cnt) {
        float* crow = part + ((size_t)sk * 4096 + off_e + slot) * HDIM + h0 + wn * 64;
#pragma unroll
        for (int ns = 0; ns < 4; ns++)
          crow[ns * 16 + lrow] = acc[ms][ns][reg];
      }
    }
  }
}

// ---------------- combine: out[t] = sum_k w_k * sum_sk part[sk][g_k] ----------------
__global__ void combine_kernel(const float* __restrict__ part,
                               const int* __restrict__ slot_of,
                               const float* __restrict__ top_w,
                               float* __restrict__ out) {
  int t = blockIdx.x;
  int g0 = slot_of[t * 2], g1 = slot_of[t * 2 + 1];
  float w0 = top_w[t * 2], w1 = top_w[t * 2 + 1];
  int i = threadIdx.x;   // 256 threads x float4 = 1024 floats
  float4 s0 = {0.f, 0.f, 0.f, 0.f}, s1 = {0.f, 0.f, 0.f, 0.f};
#pragma unroll
  for (int sk = 0; sk < SPLITK; sk++) {
    float4 a = ((const float4*)(part + ((size_t)sk * 4096 + g0) * HDIM))[i];
    float4 b = ((const float4*)(part + ((size_t)sk * 4096 + g1) * HDIM))[i];
    s0.x += a.x; s0.y += a.y; s0.z += a.z; s0.w += a.w;
    s1.x += b.x; s1.y += b.y; s1.z += b.z; s1.w += b.w;
  }
  float4 r;
  r.x = w0 * s0.x + w1 * s1.x;
  r.y = w0 * s0.y + w1 * s1.y;
  r.z = w0 * s0.z + w1 * s1.z;
  r.w = w0 * s0.w + w1 * s1.w;
  ((float4*)(out + (size_t)t * HDIM))[i] = r;
}

// ---------------- launcher ----------------
extern "C" void kernel_launch(void* const* d_in, const int* in_sizes, int n_in,
                              void* d_out, int out_size, void* d_ws, size_t ws_size,
                              hipStream_t stream) {
  const float* x  = (const float*)d_in[0];
  const float* gw = (const float*)d_in[1];
  const float* w1 = (const float*)d_in[2];
  const float* w3 = (const float*)d_in[3];
  const float* w2 = (const float*)d_in[4];
  float* out = (float*)d_out;

  char* ws = (char*)d_ws;
  const size_t MB = 1ull << 20;
  // layout (206 MB total):
  //   [0,1)    small buffers
  //   [1,5)    xbf (4 MB)
  //   [5,35)   act  (28 MB used)
  //   [35,91)  w2bf (56 MB)
  //   [94,150) w1bf (56 MB)   }-- both dead after gemm1;
  //   [150,206) w3bf (56 MB)  }   part (32 MB, SPLITK=2) aliases [94,126)
  float* top_w = (float*)(ws);
  int* top_e   = (int*)(ws + 16384);
  int* slot_of = (int*)(ws + 32768);
  int* tok_of  = (int*)(ws + 49152);
  int* count   = (int*)(ws + 65536);
  int* offs    = (int*)(ws + 65536 + 64);

  unsigned short* xbf = (unsigned short*)(ws + 1 * MB);
  unsigned short* act = (unsigned short*)(ws + 5 * MB);
  unsigned short* w2b = (unsigned short*)(ws + 35 * MB);
  unsigned short* w1b = (unsigned short*)(ws + 94 * MB);
  unsigned short* w3b = (unsigned short*)(ws + 150 * MB);
  float* part = (float*)(ws + 94 * MB);   // aliases w1b (dead after gemm1)

  gate_kernel<<<TOKENS / 4, 256, 0, stream>>>(x, gw, top_e, top_w);
  route_kernel<<<1, 1024, 0, stream>>>(top_e, count, offs, tok_of, slot_of);
  xconv_kernel<<<(TOKENS * HDIM) / (256 * 4), 256, 0, stream>>>(x, xbf);
  wconv_kernel<<<dim3(WCONV_BLK, 3), 256, 0, stream>>>(w1, w3, w2, w1b, w3b, w2b);
  gemm1_kernel<<<dim3(FDIM / G1_BF, TOKENS / G1_BM, NEXP), 256, 0, stream>>>(
      xbf, w1b, w3b, count, offs, tok_of, act);
  gemm2_kernel<<<dim3(HDIM / G2_BN, TOKENS / G2_BM, NEXP * SPLITK), 256, 0, stream>>>(
      act, w2b, count, offs, part);
  combine_kernel<<<TOKENS, 256, 0, stream>>>(part, slot_of, top_w, out);
}

// Round 8
// 508.217 us; speedup vs baseline: 1.0521x; 1.0521x over previous
//
#include <hip/hip_runtime.h>
#include <hip/hip_bf16.h>
#include <stdint.h>

#define TOKENS 2048
#define HDIM 1024
#define FDIM 3584
#define NEXP 8
#define BK 32

typedef __attribute__((ext_vector_type(8))) short short8;
typedef __attribute__((ext_vector_type(4))) float floatx4;

#define AS1 __attribute__((address_space(1)))
#define AS3 __attribute__((address_space(3)))

__device__ __forceinline__ void glds16(const void* g, void* l) {
  __builtin_amdgcn_global_load_lds((const AS1 void*)g, (AS3 void*)l, 16, 0, 0);
}

__device__ __forceinline__ unsigned short f2bf(float f) {
  union { float f; unsigned int u; } c; c.f = f;
  unsigned int u = c.u;
  u += 0x7fffu + ((u >> 16) & 1u);
  return (unsigned short)(u >> 16);
}

__device__ __forceinline__ unsigned int pk2bf(float a, float b) {
  __hip_bfloat162 h = __float22bfloat162_rn(make_float2(a, b));
  union { __hip_bfloat162 h; unsigned int u; } c; c.h = h;
  return c.u;
}

__device__ __forceinline__ short8 pack_bf16(float4 c0, float4 c1) {
  union { short8 s; uint4 u; } o;
  o.u.x = pk2bf(c0.x, c0.y); o.u.y = pk2bf(c0.z, c0.w);
  o.u.z = pk2bf(c1.x, c1.y); o.u.w = pk2bf(c1.z, c1.w);
  return o.s;
}

// ---------------- gating (no atomics) ----------------
__global__ void gate_kernel(const float* __restrict__ x,
                            const float* __restrict__ gw,
                            int* __restrict__ top_e,
                            float* __restrict__ top_w) {
  int wv = threadIdx.x >> 6;
  int lane = threadIdx.x & 63;
  int t = blockIdx.x * 4 + wv;
  if (t >= TOKENS) return;
  float p[NEXP];
#pragma unroll
  for (int e = 0; e < NEXP; e++) p[e] = 0.f;
  const float* xr = x + (size_t)t * HDIM;
  for (int h = lane; h < HDIM; h += 64) {
    float xv = xr[h];
    const float4* g4 = (const float4*)(gw + (size_t)h * NEXP);
    float4 a = g4[0], b = g4[1];
    p[0] += xv * a.x; p[1] += xv * a.y; p[2] += xv * a.z; p[3] += xv * a.w;
    p[4] += xv * b.x; p[5] += xv * b.y; p[6] += xv * b.z; p[7] += xv * b.w;
  }
#pragma unroll
  for (int e = 0; e < NEXP; e++) {
#pragma unroll
    for (int off = 32; off > 0; off >>= 1) p[e] += __shfl_xor(p[e], off, 64);
  }
  if (lane == 0) {
    int i0 = 0;
    for (int e = 1; e < NEXP; e++) if (p[e] > p[i0]) i0 = e;
    int i1 = (i0 == 0) ? 1 : 0;
    for (int e = 0; e < NEXP; e++) if (e != i0 && p[e] > p[i1]) i1 = e;
    float l0 = p[i0], l1 = p[i1];
    float e1 = __expf(l1 - l0);
    float s = 1.f + e1;
    top_e[t * 2] = i0; top_e[t * 2 + 1] = i1;
    top_w[t * 2] = 1.f / s; top_w[t * 2 + 1] = e1 / s;
  }
}

// ---------------- fused count + offsets + scatter (single block, LDS atomics only) ----------------
__global__ void route_kernel(const int* __restrict__ top_e,
                             int* __restrict__ count,
                             int* __restrict__ offs,
                             int* __restrict__ tok_of,
                             int* __restrict__ slot_of) {
  __shared__ int hist[NEXP];
  __shared__ int cur[NEXP];
  int tid = threadIdx.x;  // 1024 threads, 4 entries each
  if (tid < NEXP) hist[tid] = 0;
  __syncthreads();
  int e[4];
#pragma unroll
  for (int j = 0; j < 4; j++) {
    int i = tid * 4 + j;
    e[j] = top_e[i];
    atomicAdd(&hist[e[j]], 1);
  }
  __syncthreads();
  if (tid == 0) {
    int o = 0;
    for (int k = 0; k < NEXP; k++) {
      offs[k] = o; cur[k] = o; count[k] = hist[k]; o += hist[k];
    }
  }
  __syncthreads();
#pragma unroll
  for (int j = 0; j < 4; j++) {
    int i = tid * 4 + j;
    int g = atomicAdd(&cur[e[j]], 1);
    tok_of[g] = i >> 1;
    slot_of[i] = g;
  }
}

// ---------------- x conversion (8 MB, tiny) ----------------
__global__ void xconv_kernel(const float* __restrict__ x,
                             unsigned short* __restrict__ xbf) {
  int i = (blockIdx.x * blockDim.x + threadIdx.x) * 4;
  float4 v = *(const float4*)(x + i);
  uint2 pk;
  pk.x = pk2bf(v.x, v.y);
  pk.y = pk2bf(v.z, v.w);
  *(uint2*)(xbf + i) = pk;
}

// ---------------- GEMM1: act = silu(X w1^T) * (X w3^T), 128x64 tile ----------------
// A (bf16 x): glds16, chunk-swizzle s = q ^ ((r>>1)&3).
// B (fp32 w1/w3): register-staged fp32->bf16 conversion fused into staging;
// ds_write_b128 into the SAME swizzled layout. 2-phase double-buffer, one
// barrier per K-step; B loads issued before MFMA (latency hides under compute).
#define G1_BM 128
#define G1_BF 64

__global__ __launch_bounds__(256, 3)
void gemm1_kernel(const unsigned short* __restrict__ xbf,
                  const float* __restrict__ w1,
                  const float* __restrict__ w3,
                  const int* __restrict__ count,
                  const int* __restrict__ offs,
                  const int* __restrict__ tok_of,
                  unsigned short* __restrict__ act) {
  int e = blockIdx.z;
  int cnt = count[e];
  int m0 = blockIdx.y * G1_BM;
  if (m0 >= cnt) return;
  int f0 = blockIdx.x * G1_BF;
  int off_e = offs[e];

  __shared__ __align__(16) unsigned short sA[2 * G1_BM * 32];   // 2 x 8 KB
  __shared__ __align__(16) unsigned short sB1[2 * G1_BF * 32];  // 2 x 4 KB
  __shared__ __align__(16) unsigned short sB3[2 * G1_BF * 32];  // 2 x 4 KB

  int tid = threadIdx.x;
  int lane = tid & 63, wv = tid >> 6;

  // A staging: 512 chunks -> 2 per thread (glds16, wave-uniform LDS base)
  const unsigned short* ag[2];
  char* alb[2];
#pragma unroll
  for (int p = 0; p < 2; p++) {
    int c = tid + p * 256;
    int row = c >> 2, slot = c & 3;
    int gch = slot ^ ((row >> 1) & 3);
    int r = m0 + row;
    int tok = tok_of[off_e + (r < cnt ? r : 0)];
    ag[p] = xbf + (size_t)tok * HDIM + gch * 8;
    alb[p] = (char*)sA + (wv * 64 + p * 256) * 16;
  }
  // B staging: 256 chunks each, 1 per thread: read 8 fp32, write 8 bf16 (16B)
  const float *b1g, *b3g;
  unsigned short *b1l, *b3l;
  {
    int row = tid >> 2, slot = tid & 3;
    int gch = slot ^ ((row >> 1) & 3);
    size_t wrow = (size_t)e * FDIM + f0 + row;
    b1g = w1 + wrow * HDIM + gch * 8;
    b3g = w3 + wrow * HDIM + gch * 8;
    b1l = sB1 + tid * 8;   // elem offset = chunk (row,slot) at row*32 + slot*8
    b3l = sB3 + tid * 8;
  }

  int lrow = lane & 15, quad = lane >> 4;
  int wm = wv >> 1, wn = wv & 1;

  floatx4 acc1[4][2], acc3[4][2];
#pragma unroll
  for (int i = 0; i < 4; i++)
#pragma unroll
    for (int j = 0; j < 2; j++) {
      acc1[i][j] = (floatx4){0.f, 0.f, 0.f, 0.f};
      acc3[i][j] = (floatx4){0.f, 0.f, 0.f, 0.f};
    }

  const int NT = HDIM / BK;  // 32

  // prologue: stage tile 0 into buf 0
#pragma unroll
  for (int p = 0; p < 2; p++) glds16(ag[p], alb[p]);
  {
    float4 u0 = *(const float4*)(b1g);
    float4 u1 = *(const float4*)(b1g + 4);
    float4 v0 = *(const float4*)(b3g);
    float4 v1 = *(const float4*)(b3g + 4);
    *(short8*)b1l = pack_bf16(u0, u1);
    *(short8*)b3l = pack_bf16(v0, v1);
  }
  __syncthreads();

  int cur = 0;
  for (int t = 0; t < NT; t++) {
    int nb = cur ^ 1;
    float4 u0, u1, v0, v1;
    if (t + 1 < NT) {
      int k = (t + 1) * BK;
      // issue A async staging + B fp32 loads early (overlap with MFMA)
#pragma unroll
      for (int p = 0; p < 2; p++) glds16(ag[p] + k, alb[p] + nb * 8192);
      u0 = *(const float4*)(b1g + k);
      u1 = *(const float4*)(b1g + k + 4);
      v0 = *(const float4*)(b3g + k);
      v1 = *(const float4*)(b3g + k + 4);
    }

    const unsigned short* sAc = sA + cur * (G1_BM * 32);
    const unsigned short* sB1c = sB1 + cur * (G1_BF * 32);
    const unsigned short* sB3c = sB3 + cur * (G1_BF * 32);

    short8 af[4], b1f[2], b3f[2];
#pragma unroll
    for (int ms = 0; ms < 4; ms++) {
      int r = wm * 64 + ms * 16 + lrow;
      int sl = quad ^ ((r >> 1) & 3);
      af[ms] = *(const short8*)(sAc + r * 32 + sl * 8);
    }
#pragma unroll
    for (int ns = 0; ns < 2; ns++) {
      int r = wn * 32 + ns * 16 + lrow;
      int sl = quad ^ ((r >> 1) & 3);
      b1f[ns] = *(const short8*)(sB1c + r * 32 + sl * 8);
      b3f[ns] = *(const short8*)(sB3c + r * 32 + sl * 8);
    }
#pragma unroll
    for (int ms = 0; ms < 4; ms++)
#pragma unroll
      for (int ns = 0; ns < 2; ns++) {
        acc1[ms][ns] = __builtin_amdgcn_mfma_f32_16x16x32_bf16(af[ms], b1f[ns], acc1[ms][ns], 0, 0, 0);
        acc3[ms][ns] = __builtin_amdgcn_mfma_f32_16x16x32_bf16(af[ms], b3f[ns], acc3[ms][ns], 0, 0, 0);
      }

    if (t + 1 < NT) {
      // convert + write into next buffer (ds_reads above target cur: disjoint)
      *(short8*)(b1l + nb * (G1_BF * 32)) = pack_bf16(u0, u1);
      *(short8*)(b3l + nb * (G1_BF * 32)) = pack_bf16(v0, v1);
    }
    __syncthreads();   // drains glds16 (vmcnt) + ds_write (lgkmcnt); nb ready
    cur = nb;
  }

#pragma unroll
  for (int ms = 0; ms < 4; ms++) {
#pragma unroll
    for (int reg = 0; reg < 4; reg++) {
      int slot = m0 + wm * 64 + ms * 16 + quad * 4 + reg;
      if (slot < cnt) {
        unsigned short* ar = act + (size_t)(off_e + slot) * FDIM + f0 + wn * 32;
#pragma unroll
        for (int ns = 0; ns < 2; ns++) {
          float h = acc1[ms][ns][reg];
          float g = acc3[ms][ns][reg];
          float a = h / (1.f + __expf(-h)) * g;
          ar[ns * 16 + lrow] = f2bf(a);
        }
      }
    }
  }
}

// ---------------- GEMM2: partial[sk] = act w2^T over K-slice, 128x128 tile ----------------
// A (bf16 act): glds16. B (fp32 w2): register-staged fused conversion.
#define G2_BM 128
#define G2_BN 128
#define SPLITK 2
#define G2_KS (FDIM / SPLITK)   // 1792

__global__ __launch_bounds__(256, 3)
void gemm2_kernel(const unsigned short* __restrict__ act,
                  const float* __restrict__ w2,
                  const int* __restrict__ count,
                  const int* __restrict__ offs,
                  float* __restrict__ part) {
  int zz = blockIdx.z;
  int e = zz & 7, sk = zz >> 3;
  int cnt = count[e];
  int m0 = blockIdx.y * G2_BM;
  if (m0 >= cnt) return;
  int h0 = blockIdx.x * G2_BN;
  int off_e = offs[e];
  int kb = sk * G2_KS;

  __shared__ __align__(16) unsigned short sA[2 * G2_BM * 32];  // 2 x 8 KB
  __shared__ __align__(16) unsigned short sB[2 * G2_BN * 32];  // 2 x 8 KB

  int tid = threadIdx.x;
  int lane = tid & 63, wv = tid >> 6;

  const unsigned short* ag[2];
  char* alb[2];
#pragma unroll
  for (int p = 0; p < 2; p++) {
    int c = tid + p * 256;
    int row = c >> 2, slot = c & 3;
    int gch = slot ^ ((row >> 1) & 3);
    int r = m0 + row;
    int rr = (r < cnt ? r : 0);
    ag[p] = act + (size_t)(off_e + rr) * FDIM + kb + gch * 8;
    alb[p] = (char*)sA + (wv * 64 + p * 256) * 16;
  }
  // B: 512 chunks -> 2 per thread, register-staged fp32->bf16
  const float* bg[2];
  unsigned short* bl[2];
#pragma unroll
  for (int p = 0; p < 2; p++) {
    int c = tid + p * 256;
    int row = c >> 2, slot = c & 3;
    int gch = slot ^ ((row >> 1) & 3);
    bg[p] = w2 + ((size_t)e * HDIM + h0 + row) * FDIM + kb + gch * 8;
    bl[p] = sB + c * 8;
  }

  int lrow = lane & 15, quad = lane >> 4;
  int wm = wv >> 1, wn = wv & 1;

  floatx4 acc[4][4];
#pragma unroll
  for (int i = 0; i < 4; i++)
#pragma unroll
    for (int j = 0; j < 4; j++) acc[i][j] = (floatx4){0.f, 0.f, 0.f, 0.f};

  const int NT = G2_KS / BK;  // 56

  // prologue
#pragma unroll
  for (int p = 0; p < 2; p++) glds16(ag[p], alb[p]);
#pragma unroll
  for (int p = 0; p < 2; p++) {
    float4 u0 = *(const float4*)(bg[p]);
    float4 u1 = *(const float4*)(bg[p] + 4);
    *(short8*)(bl[p]) = pack_bf16(u0, u1);
  }
  __syncthreads();

  int cur = 0;
  for (int t = 0; t < NT; t++) {
    int nb = cur ^ 1;
    float4 u0[2], u1[2];
    if (t + 1 < NT) {
      int k = (t + 1) * BK;
#pragma unroll
      for (int p = 0; p < 2; p++) glds16(ag[p] + k, alb[p] + nb * 8192);
#pragma unroll
      for (int p = 0; p < 2; p++) {
        u0[p] = *(const float4*)(bg[p] + k);
        u1[p] = *(const float4*)(bg[p] + k + 4);
      }
    }

    const unsigned short* sAc = sA + cur * (G2_BM * 32);
    const unsigned short* sBc = sB + cur * (G2_BN * 32);

    short8 af[4], bf[4];
#pragma unroll
    for (int ms = 0; ms < 4; ms++) {
      int r = wm * 64 + ms * 16 + lrow;
      int sl = quad ^ ((r >> 1) & 3);
      af[ms] = *(const short8*)(sAc + r * 32 + sl * 8);
    }
#pragma unroll
    for (int ns = 0; ns < 4; ns++) {
      int r = wn * 64 + ns * 16 + lrow;
      int sl = quad ^ ((r >> 1) & 3);
      bf[ns] = *(const short8*)(sBc + r * 32 + sl * 8);
    }
#pragma unroll
    for (int ms = 0; ms < 4; ms++)
#pragma unroll
      for (int ns = 0; ns < 4; ns++)
        acc[ms][ns] = __builtin_amdgcn_mfma_f32_16x16x32_bf16(af[ms], bf[ns], acc[ms][ns], 0, 0, 0);

    if (t + 1 < NT) {
#pragma unroll
      for (int p = 0; p < 2; p++)
        *(short8*)(bl[p] + nb * (G2_BN * 32)) = pack_bf16(u0[p], u1[p]);
    }
    __syncthreads();
    cur = nb;
  }

#pragma unroll
  for (int ms = 0; ms < 4; ms++) {
#pragma unroll
    for (int reg = 0; reg < 4; reg++) {
      int slot = m0 + wm * 64 + ms * 16 + quad * 4 + reg;
      if (slot < cnt) {
        float* crow = part + ((size_t)sk * 4096 + off_e + slot) * HDIM + h0 + wn * 64;
#pragma unroll
        for (int ns = 0; ns < 4; ns++)
          crow[ns * 16 + lrow] = acc[ms][ns][reg];
      }
    }
  }
}

// ---------------- combine: out[t] = sum_k w_k * sum_sk part[sk][g_k] ----------------
__global__ void combine_kernel(const float* __restrict__ part,
                               const int* __restrict__ slot_of,
                               const float* __restrict__ top_w,
                               float* __restrict__ out) {
  int t = blockIdx.x;
  int g0 = slot_of[t * 2], g1 = slot_of[t * 2 + 1];
  float w0 = top_w[t * 2], w1 = top_w[t * 2 + 1];
  int i = threadIdx.x;   // 256 threads x float4 = 1024 floats
  float4 s0 = {0.f, 0.f, 0.f, 0.f}, s1 = {0.f, 0.f, 0.f, 0.f};
#pragma unroll
  for (int sk = 0; sk < SPLITK; sk++) {
    float4 a = ((const float4*)(part + ((size_t)sk * 4096 + g0) * HDIM))[i];
    float4 b = ((const float4*)(part + ((size_t)sk * 4096 + g1) * HDIM))[i];
    s0.x += a.x; s0.y += a.y; s0.z += a.z; s0.w += a.w;
    s1.x += b.x; s1.y += b.y; s1.z += b.z; s1.w += b.w;
  }
  float4 r;
  r.x = w0 * s0.x + w1 * s1.x;
  r.y = w0 * s0.y + w1 * s1.y;
  r.z = w0 * s0.z + w1 * s1.z;
  r.w = w0 * s0.w + w1 * s1.w;
  ((float4*)(out + (size_t)t * HDIM))[i] = r;
}

// ---------------- launcher ----------------
extern "C" void kernel_launch(void* const* d_in, const int* in_sizes, int n_in,
                              void* d_out, int out_size, void* d_ws, size_t ws_size,
                              hipStream_t stream) {
  const float* x  = (const float*)d_in[0];
  const float* gw = (const float*)d_in[1];
  const float* w1 = (const float*)d_in[2];
  const float* w3 = (const float*)d_in[3];
  const float* w2 = (const float*)d_in[4];
  float* out = (float*)d_out;

  char* ws = (char*)d_ws;
  const size_t MB = 1ull << 20;
  // layout (~67 MB total):
  //   [0,1)    small buffers
  //   [1,5)    xbf (4 MB)
  //   [5,35)   act  (28 MB used)
  //   [35,67)  part (32 MB, SPLITK=2)
  float* top_w = (float*)(ws);
  int* top_e   = (int*)(ws + 16384);
  int* slot_of = (int*)(ws + 32768);
  int* tok_of  = (int*)(ws + 49152);
  int* count   = (int*)(ws + 65536);
  int* offs    = (int*)(ws + 65536 + 64);

  unsigned short* xbf = (unsigned short*)(ws + 1 * MB);
  unsigned short* act = (unsigned short*)(ws + 5 * MB);
  float* part = (float*)(ws + 35 * MB);

  gate_kernel<<<TOKENS / 4, 256, 0, stream>>>(x, gw, top_e, top_w);
  route_kernel<<<1, 1024, 0, stream>>>(top_e, count, offs, tok_of, slot_of);
  xconv_kernel<<<(TOKENS * HDIM) / (256 * 4), 256, 0, stream>>>(x, xbf);
  gemm1_kernel<<<dim3(FDIM / G1_BF, TOKENS / G1_BM, NEXP), 256, 0, stream>>>(
      xbf, w1, w3, count, offs, tok_of, act);
  gemm2_kernel<<<dim3(HDIM / G2_BN, TOKENS / G2_BM, NEXP * SPLITK), 256, 0, stream>>>(
      act, w2, count, offs, part);
  combine_kernel<<<TOKENS, 256, 0, stream>>>(part, slot_of, top_w, out);
}

// Round 10
// 475.309 us; speedup vs baseline: 1.1250x; 1.0692x over previous
//
#include <hip/hip_runtime.h>
#include <hip/hip_bf16.h>
#include <stdint.h>

#define TOKENS 2048
#define HDIM 1024
#define FDIM 3584
#define NEXP 8
#define BK 32

typedef __attribute__((ext_vector_type(8))) short short8;
typedef __attribute__((ext_vector_type(4))) float floatx4;

#define AS1 __attribute__((address_space(1)))
#define AS3 __attribute__((address_space(3)))

__device__ __forceinline__ void glds16(const void* g, void* l) {
  __builtin_amdgcn_global_load_lds((const AS1 void*)g, (AS3 void*)l, 16, 0, 0);
}

__device__ __forceinline__ unsigned short f2bf(float f) {
  union { float f; unsigned int u; } c; c.f = f;
  unsigned int u = c.u;
  u += 0x7fffu + ((u >> 16) & 1u);
  return (unsigned short)(u >> 16);
}

__device__ __forceinline__ unsigned int pk2bf(float a, float b) {
  __hip_bfloat162 h = __float22bfloat162_rn(make_float2(a, b));
  union { __hip_bfloat162 h; unsigned int u; } c; c.h = h;
  return c.u;
}

__device__ __forceinline__ short8 pack_bf16(float4 c0, float4 c1) {
  union { short8 s; uint4 u; } o;
  o.u.x = pk2bf(c0.x, c0.y); o.u.y = pk2bf(c0.z, c0.w);
  o.u.z = pk2bf(c1.x, c1.y); o.u.w = pk2bf(c1.z, c1.w);
  return o.s;
}

// ---------------- gating + x->bf16 conversion fused (vectorized) ----------------
__global__ void gate_kernel(const float* __restrict__ x,
                            const float* __restrict__ gw,
                            unsigned short* __restrict__ xbf,
                            int* __restrict__ top_e,
                            float* __restrict__ top_w) {
  int wv = threadIdx.x >> 6;
  int lane = threadIdx.x & 63;
  int t = blockIdx.x * 4 + wv;
  if (t >= TOKENS) return;
  float p[NEXP];
#pragma unroll
  for (int e = 0; e < NEXP; e++) p[e] = 0.f;
  const float* xr = x + (size_t)t * HDIM;
  unsigned short* xb = xbf + (size_t)t * HDIM;
#pragma unroll
  for (int it = 0; it < 4; it++) {
    int h = it * 256 + lane * 4;
    float4 v = *(const float4*)(xr + h);
    uint2 pk;
    pk.x = pk2bf(v.x, v.y);
    pk.y = pk2bf(v.z, v.w);
    *(uint2*)(xb + h) = pk;
    const float* g0 = gw + (size_t)h * NEXP;
#pragma unroll
    for (int j = 0; j < 4; j++) {
      float xv = (j == 0) ? v.x : (j == 1) ? v.y : (j == 2) ? v.z : v.w;
      const float4* g4 = (const float4*)(g0 + j * NEXP);
      float4 a = g4[0], b = g4[1];
      p[0] += xv * a.x; p[1] += xv * a.y; p[2] += xv * a.z; p[3] += xv * a.w;
      p[4] += xv * b.x; p[5] += xv * b.y; p[6] += xv * b.z; p[7] += xv * b.w;
    }
  }
#pragma unroll
  for (int e = 0; e < NEXP; e++) {
#pragma unroll
    for (int off = 32; off > 0; off >>= 1) p[e] += __shfl_xor(p[e], off, 64);
  }
  if (lane == 0) {
    int i0 = 0;
    for (int e = 1; e < NEXP; e++) if (p[e] > p[i0]) i0 = e;
    int i1 = (i0 == 0) ? 1 : 0;
    for (int e = 0; e < NEXP; e++) if (e != i0 && p[e] > p[i1]) i1 = e;
    float l0 = p[i0], l1 = p[i1];
    float e1 = __expf(l1 - l0);
    float s = 1.f + e1;
    top_e[t * 2] = i0; top_e[t * 2 + 1] = i1;
    top_w[t * 2] = 1.f / s; top_w[t * 2 + 1] = e1 / s;
  }
}

// ---------------- fused count + offsets + scatter (single block, LDS atomics only) ----------------
__global__ void route_kernel(const int* __restrict__ top_e,
                             int* __restrict__ count,
                             int* __restrict__ offs,
                             int* __restrict__ tok_of,
                             int* __restrict__ slot_of) {
  __shared__ int hist[NEXP];
  __shared__ int cur[NEXP];
  int tid = threadIdx.x;  // 1024 threads, 4 entries each
  if (tid < NEXP) hist[tid] = 0;
  __syncthreads();
  int e[4];
#pragma unroll
  for (int j = 0; j < 4; j++) {
    int i = tid * 4 + j;
    e[j] = top_e[i];
    atomicAdd(&hist[e[j]], 1);
  }
  __syncthreads();
  if (tid == 0) {
    int o = 0;
    for (int k = 0; k < NEXP; k++) {
      offs[k] = o; cur[k] = o; count[k] = hist[k]; o += hist[k];
    }
  }
  __syncthreads();
#pragma unroll
  for (int j = 0; j < 4; j++) {
    int i = tid * 4 + j;
    int g = atomicAdd(&cur[e[j]], 1);
    tok_of[g] = i >> 1;
    slot_of[i] = g;
  }
}

// ---------------- GEMM1: act = silu(X w1^T) * (X w3^T), 128x64 tile ----------------
// A (bf16 x): glds16, chunk-swizzle s = q ^ ((r>>1)&3).
// B (fp32 w1/w3): DISTANCE-2 register pipeline — loads for tile t+2 issued at
// step t; ds_write of tile t+1 (loaded a step earlier, drained by previous
// barrier) moved to the TOP of the step -> off the critical path. One barrier
// per K-step; VMEM latency window = one full step.
#define G1_BM 128
#define G1_BF 64

__global__ __launch_bounds__(256, 3)
void gemm1_kernel(const unsigned short* __restrict__ xbf,
                  const float* __restrict__ w1,
                  const float* __restrict__ w3,
                  const int* __restrict__ count,
                  const int* __restrict__ offs,
                  const int* __restrict__ tok_of,
                  unsigned short* __restrict__ act) {
  int e = blockIdx.z;
  int cnt = count[e];
  int m0 = blockIdx.y * G1_BM;
  if (m0 >= cnt) return;
  int f0 = blockIdx.x * G1_BF;
  int off_e = offs[e];

  __shared__ __align__(16) unsigned short sA[2 * G1_BM * 32];   // 2 x 8 KB
  __shared__ __align__(16) unsigned short sB1[2 * G1_BF * 32];  // 2 x 4 KB
  __shared__ __align__(16) unsigned short sB3[2 * G1_BF * 32];  // 2 x 4 KB

  int tid = threadIdx.x;
  int lane = tid & 63, wv = tid >> 6;

  // A staging: 512 chunks -> 2 per thread (glds16, wave-uniform LDS base)
  const unsigned short* ag[2];
  char* alb[2];
#pragma unroll
  for (int p = 0; p < 2; p++) {
    int c = tid + p * 256;
    int row = c >> 2, slot = c & 3;
    int gch = slot ^ ((row >> 1) & 3);
    int r = m0 + row;
    int tok = tok_of[off_e + (r < cnt ? r : 0)];
    ag[p] = xbf + (size_t)tok * HDIM + gch * 8;
    alb[p] = (char*)sA + (wv * 64 + p * 256) * 16;
  }
  // B staging: 256 chunks each, 1 per thread: read 8 fp32, write 8 bf16 (16B)
  const float *b1g, *b3g;
  unsigned short *b1l, *b3l;
  {
    int row = tid >> 2, slot = tid & 3;
    int gch = slot ^ ((row >> 1) & 3);
    size_t wrow = (size_t)e * FDIM + f0 + row;
    b1g = w1 + wrow * HDIM + gch * 8;
    b3g = w3 + wrow * HDIM + gch * 8;
    b1l = sB1 + tid * 8;   // elem offset = chunk (row,slot) at row*32 + slot*8
    b3l = sB3 + tid * 8;
  }

  int lrow = lane & 15, quad = lane >> 4;
  int wm = wv >> 1, wn = wv & 1;

  floatx4 acc1[4][2], acc3[4][2];
#pragma unroll
  for (int i = 0; i < 4; i++)
#pragma unroll
    for (int j = 0; j < 2; j++) {
      acc1[i][j] = (floatx4){0.f, 0.f, 0.f, 0.f};
      acc3[i][j] = (floatx4){0.f, 0.f, 0.f, 0.f};
    }

  const int NT = HDIM / BK;  // 32

  // prologue: stage tile 0 into buf 0 + preload B(1) into regs
#pragma unroll
  for (int p = 0; p < 2; p++) glds16(ag[p], alb[p]);
  {
    float4 a0 = *(const float4*)(b1g), a1 = *(const float4*)(b1g + 4);
    float4 c0 = *(const float4*)(b3g), c1 = *(const float4*)(b3g + 4);
    *(short8*)b1l = pack_bf16(a0, a1);
    *(short8*)b3l = pack_bf16(c0, c1);
  }
  float4 cu0 = *(const float4*)(b1g + BK), cu1 = *(const float4*)(b1g + BK + 4);
  float4 cv0 = *(const float4*)(b3g + BK), cv1 = *(const float4*)(b3g + BK + 4);
  __syncthreads();

  int cur = 0;
  for (int t = 0; t < NT; t++) {
    int nb = cur ^ 1;
    if (t + 1 < NT) {
      // B(t+1) regs were loaded at step t-1 and drained by the previous
      // barrier -> this ds_write has zero wait. nb's readers finished before
      // that barrier too, so writing early is safe.
      *(short8*)(b1l + nb * (G1_BF * 32)) = pack_bf16(cu0, cu1);
      *(short8*)(b3l + nb * (G1_BF * 32)) = pack_bf16(cv0, cv1);
      int k = (t + 1) * BK;
#pragma unroll
      for (int p = 0; p < 2; p++) glds16(ag[p] + k, alb[p] + nb * 8192);
    }
    float4 nu0 = {0.f, 0.f, 0.f, 0.f}, nu1 = {0.f, 0.f, 0.f, 0.f};
    float4 nv0 = {0.f, 0.f, 0.f, 0.f}, nv1 = {0.f, 0.f, 0.f, 0.f};
    if (t + 2 < NT) {
      int k2 = (t + 2) * BK;
      nu0 = *(const float4*)(b1g + k2); nu1 = *(const float4*)(b1g + k2 + 4);
      nv0 = *(const float4*)(b3g + k2); nv1 = *(const float4*)(b3g + k2 + 4);
    }

    const unsigned short* sAc = sA + cur * (G1_BM * 32);
    const unsigned short* sB1c = sB1 + cur * (G1_BF * 32);
    const unsigned short* sB3c = sB3 + cur * (G1_BF * 32);

    short8 af[4], b1f[2], b3f[2];
#pragma unroll
    for (int ms = 0; ms < 4; ms++) {
      int r = wm * 64 + ms * 16 + lrow;
      int sl = quad ^ ((r >> 1) & 3);
      af[ms] = *(const short8*)(sAc + r * 32 + sl * 8);
    }
#pragma unroll
    for (int ns = 0; ns < 2; ns++) {
      int r = wn * 32 + ns * 16 + lrow;
      int sl = quad ^ ((r >> 1) & 3);
      b1f[ns] = *(const short8*)(sB1c + r * 32 + sl * 8);
      b3f[ns] = *(const short8*)(sB3c + r * 32 + sl * 8);
    }
#pragma unroll
    for (int ms = 0; ms < 4; ms++)
#pragma unroll
      for (int ns = 0; ns < 2; ns++) {
        acc1[ms][ns] = __builtin_amdgcn_mfma_f32_16x16x32_bf16(af[ms], b1f[ns], acc1[ms][ns], 0, 0, 0);
        acc3[ms][ns] = __builtin_amdgcn_mfma_f32_16x16x32_bf16(af[ms], b3f[ns], acc3[ms][ns], 0, 0, 0);
      }

    cu0 = nu0; cu1 = nu1; cv0 = nv0; cv1 = nv1;
    __syncthreads();   // drains glds16 (vmcnt) + ds_write (lgkmcnt); nb ready
    cur = nb;
  }

#pragma unroll
  for (int ms = 0; ms < 4; ms++) {
#pragma unroll
    for (int reg = 0; reg < 4; reg++) {
      int slot = m0 + wm * 64 + ms * 16 + quad * 4 + reg;
      if (slot < cnt) {
        unsigned short* ar = act + (size_t)(off_e + slot) * FDIM + f0 + wn * 32;
#pragma unroll
        for (int ns = 0; ns < 2; ns++) {
          float h = acc1[ms][ns][reg];
          float g = acc3[ms][ns][reg];
          float a = h / (1.f + __expf(-h)) * g;
          ar[ns * 16 + lrow] = f2bf(a);
        }
      }
    }
  }
}

// ---------------- GEMM2: partial[sk] = act w2^T over K-slice, 128x128 tile ----------------
// A (bf16 act): glds16. B (fp32 w2): distance-2 register pipeline, early ds_write.
#define G2_BM 128
#define G2_BN 128
#define SPLITK 2
#define G2_KS (FDIM / SPLITK)   // 1792

__global__ __launch_bounds__(256, 3)
void gemm2_kernel(const unsigned short* __restrict__ act,
                  const float* __restrict__ w2,
                  const int* __restrict__ count,
                  const int* __restrict__ offs,
                  float* __restrict__ part) {
  int zz = blockIdx.z;
  int e = zz & 7, sk = zz >> 3;
  int cnt = count[e];
  int m0 = blockIdx.y * G2_BM;
  if (m0 >= cnt) return;
  int h0 = blockIdx.x * G2_BN;
  int off_e = offs[e];
  int kb = sk * G2_KS;

  __shared__ __align__(16) unsigned short sA[2 * G2_BM * 32];  // 2 x 8 KB
  __shared__ __align__(16) unsigned short sB[2 * G2_BN * 32];  // 2 x 8 KB

  int tid = threadIdx.x;
  int lane = tid & 63, wv = tid >> 6;

  const unsigned short* ag[2];
  char* alb[2];
#pragma unroll
  for (int p = 0; p < 2; p++) {
    int c = tid + p * 256;
    int row = c >> 2, slot = c & 3;
    int gch = slot ^ ((row >> 1) & 3);
    int r = m0 + row;
    int rr = (r < cnt ? r : 0);
    ag[p] = act + (size_t)(off_e + rr) * FDIM + kb + gch * 8;
    alb[p] = (char*)sA + (wv * 64 + p * 256) * 16;
  }
  // B: 512 chunks -> 2 per thread, register-staged fp32->bf16
  const float* bg[2];
  unsigned short* bl[2];
#pragma unroll
  for (int p = 0; p < 2; p++) {
    int c = tid + p * 256;
    int row = c >> 2, slot = c & 3;
    int gch = slot ^ ((row >> 1) & 3);
    bg[p] = w2 + ((size_t)e * HDIM + h0 + row) * FDIM + kb + gch * 8;
    bl[p] = sB + c * 8;
  }

  int lrow = lane & 15, quad = lane >> 4;
  int wm = wv >> 1, wn = wv & 1;

  floatx4 acc[4][4];
#pragma unroll
  for (int i = 0; i < 4; i++)
#pragma unroll
    for (int j = 0; j < 4; j++) acc[i][j] = (floatx4){0.f, 0.f, 0.f, 0.f};

  const int NT = G2_KS / BK;  // 56

  // prologue: stage tile 0 + preload B(1)
#pragma unroll
  for (int p = 0; p < 2; p++) glds16(ag[p], alb[p]);
#pragma unroll
  for (int p = 0; p < 2; p++) {
    float4 a0 = *(const float4*)(bg[p]);
    float4 a1 = *(const float4*)(bg[p] + 4);
    *(short8*)(bl[p]) = pack_bf16(a0, a1);
  }
  float4 cu0[2], cu1[2];
#pragma unroll
  for (int p = 0; p < 2; p++) {
    cu0[p] = *(const float4*)(bg[p] + BK);
    cu1[p] = *(const float4*)(bg[p] + BK + 4);
  }
  __syncthreads();

  int cur = 0;
  for (int t = 0; t < NT; t++) {
    int nb = cur ^ 1;
    if (t + 1 < NT) {
#pragma unroll
      for (int p = 0; p < 2; p++)
        *(short8*)(bl[p] + nb * (G2_BN * 32)) = pack_bf16(cu0[p], cu1[p]);
      int k = (t + 1) * BK;
#pragma unroll
      for (int p = 0; p < 2; p++) glds16(ag[p] + k, alb[p] + nb * 8192);
    }
    float4 nu0[2], nu1[2];
#pragma unroll
    for (int p = 0; p < 2; p++) {
      nu0[p] = (float4){0.f, 0.f, 0.f, 0.f};
      nu1[p] = (float4){0.f, 0.f, 0.f, 0.f};
    }
    if (t + 2 < NT) {
      int k2 = (t + 2) * BK;
#pragma unroll
      for (int p = 0; p < 2; p++) {
        nu0[p] = *(const float4*)(bg[p] + k2);
        nu1[p] = *(const float4*)(bg[p] + k2 + 4);
      }
    }

    const unsigned short* sAc = sA + cur * (G2_BM * 32);
    const unsigned short* sBc = sB + cur * (G2_BN * 32);

    short8 af[4], bf[4];
#pragma unroll
    for (int ms = 0; ms < 4; ms++) {
      int r = wm * 64 + ms * 16 + lrow;
      int sl = quad ^ ((r >> 1) & 3);
      af[ms] = *(const short8*)(sAc + r * 32 + sl * 8);
    }
#pragma unroll
    for (int ns = 0; ns < 4; ns++) {
      int r = wn * 64 + ns * 16 + lrow;
      int sl = quad ^ ((r >> 1) & 3);
      bf[ns] = *(const short8*)(sBc + r * 32 + sl * 8);
    }
#pragma unroll
    for (int ms = 0; ms < 4; ms++)
#pragma unroll
      for (int ns = 0; ns < 4; ns++)
        acc[ms][ns] = __builtin_amdgcn_mfma_f32_16x16x32_bf16(af[ms], bf[ns], acc[ms][ns], 0, 0, 0);

#pragma unroll
    for (int p = 0; p < 2; p++) { cu0[p] = nu0[p]; cu1[p] = nu1[p]; }
    __syncthreads();
    cur = nb;
  }

#pragma unroll
  for (int ms = 0; ms < 4; ms++) {
#pragma unroll
    for (int reg = 0; reg < 4; reg++) {
      int slot = m0 + wm * 64 + ms * 16 + quad * 4 + reg;
      if (slot < cnt) {
        float* crow = part + ((size_t)sk * 4096 + off_e + slot) * HDIM + h0 + wn * 64;
#pragma unroll
        for (int ns = 0; ns < 4; ns++)
          crow[ns * 16 + lrow] = acc[ms][ns][reg];
      }
    }
  }
}

// ---------------- combine: out[t] = sum_k w_k * sum_sk part[sk][g_k] ----------------
__global__ void combine_kernel(const float* __restrict__ part,
                               const int* __restrict__ slot_of,
                               const float* __restrict__ top_w,
                               float* __restrict__ out) {
  int t = blockIdx.x;
  int g0 = slot_of[t * 2], g1 = slot_of[t * 2 + 1];
  float w0 = top_w[t * 2], w1 = top_w[t * 2 + 1];
  int i = threadIdx.x;   // 256 threads x float4 = 1024 floats
  float4 s0 = {0.f, 0.f, 0.f, 0.f}, s1 = {0.f, 0.f, 0.f, 0.f};
#pragma unroll
  for (int sk = 0; sk < SPLITK; sk++) {
    float4 a = ((const float4*)(part + ((size_t)sk * 4096 + g0) * HDIM))[i];
    float4 b = ((const float4*)(part + ((size_t)sk * 4096 + g1) * HDIM))[i];
    s0.x += a.x; s0.y += a.y; s0.z += a.z; s0.w += a.w;
    s1.x += b.x; s1.y += b.y; s1.z += b.z; s1.w += b.w;
  }
  float4 r;
  r.x = w0 * s0.x + w1 * s1.x;
  r.y = w0 * s0.y + w1 * s1.y;
  r.z = w0 * s0.z + w1 * s1.z;
  r.w = w0 * s0.w + w1 * s1.w;
  ((float4*)(out + (size_t)t * HDIM))[i] = r;
}

// ---------------- launcher ----------------
extern "C" void kernel_launch(void* const* d_in, const int* in_sizes, int n_in,
                              void* d_out, int out_size, void* d_ws, size_t ws_size,
                              hipStream_t stream) {
  const float* x  = (const float*)d_in[0];
  const float* gw = (const float*)d_in[1];
  const float* w1 = (const float*)d_in[2];
  const float* w3 = (const float*)d_in[3];
  const float* w2 = (const float*)d_in[4];
  float* out = (float*)d_out;

  char* ws = (char*)d_ws;
  const size_t MB = 1ull << 20;
  // layout (~67 MB total):
  //   [0,1)    small buffers
  //   [1,5)    xbf (4 MB)
  //   [5,35)   act  (28 MB used)
  //   [35,67)  part (32 MB, SPLITK=2)
  float* top_w = (float*)(ws);
  int* top_e   = (int*)(ws + 16384);
  int* slot_of = (int*)(ws + 32768);
  int* tok_of  = (int*)(ws + 49152);
  int* count   = (int*)(ws + 65536);
  int* offs    = (int*)(ws + 65536 + 64);

  unsigned short* xbf = (unsigned short*)(ws + 1 * MB);
  unsigned short* act = (unsigned short*)(ws + 5 * MB);
  float* part = (float*)(ws + 35 * MB);

  gate_kernel<<<TOKENS / 4, 256, 0, stream>>>(x, gw, xbf, top_e, top_w);
  route_kernel<<<1, 1024, 0, stream>>>(top_e, count, offs, tok_of, slot_of);
  gemm1_kernel<<<dim3(FDIM / G1_BF, TOKENS / G1_BM, NEXP), 256, 0, stream>>>(
      xbf, w1, w3, count, offs, tok_of, act);
  gemm2_kernel<<<dim3(HDIM / G2_BN, TOKENS / G2_BM, NEXP * SPLITK), 256, 0, stream>>>(
      act, w2, count, offs, part);
  combine_kernel<<<TOKENS, 256, 0, stream>>>(part, slot_of, top_w, out);
}

// Round 13
// 472.735 us; speedup vs baseline: 1.1311x; 1.0054x over previous
//
#include <hip/hip_runtime.h>
#include <hip/hip_bf16.h>
#include <stdint.h>

#define TOKENS 2048
#define HDIM 1024
#define FDIM 3584
#define NEXP 8
#define BK 32

typedef __attribute__((ext_vector_type(8))) short short8;
typedef __attribute__((ext_vector_type(4))) float floatx4;

#define AS1 __attribute__((address_space(1)))
#define AS3 __attribute__((address_space(3)))

__device__ __forceinline__ void glds16(const void* g, void* l) {
  __builtin_amdgcn_global_load_lds((const AS1 void*)g, (AS3 void*)l, 16, 0, 0);
}

// Raw barrier with COUNTED vmcnt: waits the 2 glds16 (oldest) but leaves the
// 4 B-prefetch loads in flight across the barrier. lgkmcnt(0) makes this
// step's ds_writes visible. sched_barrier fences per guide rule #18.
#define PIPE_BARRIER() do {                                        \
  asm volatile("s_waitcnt vmcnt(4) lgkmcnt(0)" ::: "memory");      \
  __builtin_amdgcn_sched_barrier(0);                               \
  __builtin_amdgcn_s_barrier();                                    \
  __builtin_amdgcn_sched_barrier(0);                               \
} while (0)

__device__ __forceinline__ unsigned short f2bf(float f) {
  union { float f; unsigned int u; } c; c.f = f;
  unsigned int u = c.u;
  u += 0x7fffu + ((u >> 16) & 1u);
  return (unsigned short)(u >> 16);
}

__device__ __forceinline__ unsigned int pk2bf(float a, float b) {
  __hip_bfloat162 h = __float22bfloat162_rn(make_float2(a, b));
  union { __hip_bfloat162 h; unsigned int u; } c; c.h = h;
  return c.u;
}

__device__ __forceinline__ short8 pack_bf16(float4 c0, float4 c1) {
  union { short8 s; uint4 u; } o;
  o.u.x = pk2bf(c0.x, c0.y); o.u.y = pk2bf(c0.z, c0.w);
  o.u.z = pk2bf(c1.x, c1.y); o.u.w = pk2bf(c1.z, c1.w);
  return o.s;
}

// ---------------- gating + x->bf16 conversion fused (vectorized) ----------------
__global__ void gate_kernel(const float* __restrict__ x,
                            const float* __restrict__ gw,
                            unsigned short* __restrict__ xbf,
                            int* __restrict__ top_e,
                            float* __restrict__ top_w) {
  int wv = threadIdx.x >> 6;
  int lane = threadIdx.x & 63;
  int t = blockIdx.x * 4 + wv;
  if (t >= TOKENS) return;
  float p[NEXP];
#pragma unroll
  for (int e = 0; e < NEXP; e++) p[e] = 0.f;
  const float* xr = x + (size_t)t * HDIM;
  unsigned short* xb = xbf + (size_t)t * HDIM;
#pragma unroll
  for (int it = 0; it < 4; it++) {
    int h = it * 256 + lane * 4;
    float4 v = *(const float4*)(xr + h);
    uint2 pk;
    pk.x = pk2bf(v.x, v.y);
    pk.y = pk2bf(v.z, v.w);
    *(uint2*)(xb + h) = pk;
    const float* g0 = gw + (size_t)h * NEXP;
#pragma unroll
    for (int j = 0; j < 4; j++) {
      float xv = (j == 0) ? v.x : (j == 1) ? v.y : (j == 2) ? v.z : v.w;
      const float4* g4 = (const float4*)(g0 + j * NEXP);
      float4 a = g4[0], b = g4[1];
      p[0] += xv * a.x; p[1] += xv * a.y; p[2] += xv * a.z; p[3] += xv * a.w;
      p[4] += xv * b.x; p[5] += xv * b.y; p[6] += xv * b.z; p[7] += xv * b.w;
    }
  }
#pragma unroll
  for (int e = 0; e < NEXP; e++) {
#pragma unroll
    for (int off = 32; off > 0; off >>= 1) p[e] += __shfl_xor(p[e], off, 64);
  }
  if (lane == 0) {
    int i0 = 0;
    for (int e = 1; e < NEXP; e++) if (p[e] > p[i0]) i0 = e;
    int i1 = (i0 == 0) ? 1 : 0;
    for (int e = 0; e < NEXP; e++) if (e != i0 && p[e] > p[i1]) i1 = e;
    float l0 = p[i0], l1 = p[i1];
    float e1 = __expf(l1 - l0);
    float s = 1.f + e1;
    top_e[t * 2] = i0; top_e[t * 2 + 1] = i1;
    top_w[t * 2] = 1.f / s; top_w[t * 2 + 1] = e1 / s;
  }
}

// ---------------- fused count + offsets + scatter (single block, LDS atomics only) ----------------
__global__ void route_kernel(const int* __restrict__ top_e,
                             int* __restrict__ count,
                             int* __restrict__ offs,
                             int* __restrict__ tok_of,
                             int* __restrict__ slot_of) {
  __shared__ int hist[NEXP];
  __shared__ int cur[NEXP];
  int tid = threadIdx.x;  // 1024 threads, 4 entries each
  if (tid < NEXP) hist[tid] = 0;
  __syncthreads();
  int e[4];
#pragma unroll
  for (int j = 0; j < 4; j++) {
    int i = tid * 4 + j;
    e[j] = top_e[i];
    atomicAdd(&hist[e[j]], 1);
  }
  __syncthreads();
  if (tid == 0) {
    int o = 0;
    for (int k = 0; k < NEXP; k++) {
      offs[k] = o; cur[k] = o; count[k] = hist[k]; o += hist[k];
    }
  }
  __syncthreads();
#pragma unroll
  for (int j = 0; j < 4; j++) {
    int i = tid * 4 + j;
    int g = atomicAdd(&cur[e[j]], 1);
    tok_of[g] = i >> 1;
    slot_of[i] = g;
  }
}

// ---------------- GEMM1: act = silu(X w1^T) * (X w3^T), 128x64 tile ----------------
// A (bf16 x): glds16, chunk-swizzle s = q ^ ((r>>1)&3).
// B (fp32 w1/w3): distance-2 register pipeline; the raw-barrier + vmcnt(4)
// lets the B(t+2) loads stay in flight ACROSS the barrier (a full K-step
// window). Loop is uniform (clamped addrs) so outstanding-count at the
// barrier is always 2 glds + 4 B-loads = 6 -> vmcnt(4) waits exactly the glds.
#define G1_BM 128
#define G1_BF 64

__global__ __launch_bounds__(256, 3)
void gemm1_kernel(const unsigned short* __restrict__ xbf,
                  const float* __restrict__ w1,
                  const float* __restrict__ w3,
                  const int* __restrict__ count,
                  const int* __restrict__ offs,
                  const int* __restrict__ tok_of,
                  unsigned short* __restrict__ act) {
  int e = blockIdx.z;
  int cnt = count[e];
  int m0 = blockIdx.y * G1_BM;
  if (m0 >= cnt) return;
  int f0 = blockIdx.x * G1_BF;
  int off_e = offs[e];

  __shared__ __align__(16) unsigned short sA[2 * G1_BM * 32];   // 2 x 8 KB
  __shared__ __align__(16) unsigned short sB1[2 * G1_BF * 32];  // 2 x 4 KB
  __shared__ __align__(16) unsigned short sB3[2 * G1_BF * 32];  // 2 x 4 KB

  int tid = threadIdx.x;
  int lane = tid & 63, wv = tid >> 6;

  const unsigned short* ag[2];
  char* alb[2];
#pragma unroll
  for (int p = 0; p < 2; p++) {
    int c = tid + p * 256;
    int row = c >> 2, slot = c & 3;
    int gch = slot ^ ((row >> 1) & 3);
    int r = m0 + row;
    int tok = tok_of[off_e + (r < cnt ? r : 0)];
    ag[p] = xbf + (size_t)tok * HDIM + gch * 8;
    alb[p] = (char*)sA + (wv * 64 + p * 256) * 16;
  }
  const float *b1g, *b3g;
  unsigned short *b1l, *b3l;
  {
    int row = tid >> 2, slot = tid & 3;
    int gch = slot ^ ((row >> 1) & 3);
    size_t wrow = (size_t)e * FDIM + f0 + row;
    b1g = w1 + wrow * HDIM + gch * 8;
    b3g = w3 + wrow * HDIM + gch * 8;
    b1l = sB1 + tid * 8;
    b3l = sB3 + tid * 8;
  }

  int lrow = lane & 15, quad = lane >> 4;
  int wm = wv >> 1, wn = wv & 1;

  floatx4 acc1[4][2], acc3[4][2];
#pragma unroll
  for (int i = 0; i < 4; i++)
#pragma unroll
    for (int j = 0; j < 2; j++) {
      acc1[i][j] = (floatx4){0.f, 0.f, 0.f, 0.f};
      acc3[i][j] = (floatx4){0.f, 0.f, 0.f, 0.f};
    }

  const int NT = HDIM / BK;  // 32

  // prologue: stage tile 0 into buf 0 + preload B(1) into regs
#pragma unroll
  for (int p = 0; p < 2; p++) glds16(ag[p], alb[p]);
  asm volatile("" ::: "memory");   // glds stay older than the loads below
  {
    float4 a0 = *(const float4*)(b1g), a1 = *(const float4*)(b1g + 4);
    float4 c0 = *(const float4*)(b3g), c1 = *(const float4*)(b3g + 4);
    *(short8*)b1l = pack_bf16(a0, a1);
    *(short8*)b3l = pack_bf16(c0, c1);
  }
  float4 cu0 = *(const float4*)(b1g + BK), cu1 = *(const float4*)(b1g + BK + 4);
  float4 cv0 = *(const float4*)(b3g + BK), cv1 = *(const float4*)(b3g + BK + 4);
  PIPE_BARRIER();

  int cur = 0;
  for (int t = 0; t < NT; t++) {
    int nb = cur ^ 1;
    // B(t+1): regs aged one full step + barrier; compiler waits their vmcnt.
    *(short8*)(b1l + nb * (G1_BF * 32)) = pack_bf16(cu0, cu1);
    *(short8*)(b3l + nb * (G1_BF * 32)) = pack_bf16(cv0, cv1);
    // A(t+1) glds issued FIRST -> they are the ops vmcnt(4) waits for.
    int k1 = (t + 1 < NT) ? (t + 1) * BK : 0;
#pragma unroll
    for (int p = 0; p < 2; p++) glds16(ag[p] + k1, alb[p] + nb * 8192);
    asm volatile("" ::: "memory");
    // B(t+2) prefetch: stays in flight across the barrier.
    int k2 = (t + 2 < NT) ? (t + 2) * BK : 0;
    float4 nu0 = *(const float4*)(b1g + k2);
    float4 nu1 = *(const float4*)(b1g + k2 + 4);
    float4 nv0 = *(const float4*)(b3g + k2);
    float4 nv1 = *(const float4*)(b3g + k2 + 4);

    const unsigned short* sAc = sA + cur * (G1_BM * 32);
    const unsigned short* sB1c = sB1 + cur * (G1_BF * 32);
    const unsigned short* sB3c = sB3 + cur * (G1_BF * 32);

    short8 af[4], b1f[2], b3f[2];
#pragma unroll
    for (int ms = 0; ms < 4; ms++) {
      int r = wm * 64 + ms * 16 + lrow;
      int sl = quad ^ ((r >> 1) & 3);
      af[ms] = *(const short8*)(sAc + r * 32 + sl * 8);
    }
#pragma unroll
    for (int ns = 0; ns < 2; ns++) {
      int r = wn * 32 + ns * 16 + lrow;
      int sl = quad ^ ((r >> 1) & 3);
      b1f[ns] = *(const short8*)(sB1c + r * 32 + sl * 8);
      b3f[ns] = *(const short8*)(sB3c + r * 32 + sl * 8);
    }
#pragma unroll
    for (int ms = 0; ms < 4; ms++)
#pragma unroll
      for (int ns = 0; ns < 2; ns++) {
        acc1[ms][ns] = __builtin_amdgcn_mfma_f32_16x16x32_bf16(af[ms], b1f[ns], acc1[ms][ns], 0, 0, 0);
        acc3[ms][ns] = __builtin_amdgcn_mfma_f32_16x16x32_bf16(af[ms], b3f[ns], acc3[ms][ns], 0, 0, 0);
      }

    cu0 = nu0; cu1 = nu1; cv0 = nv0; cv1 = nv1;
    PIPE_BARRIER();
    cur = nb;
  }

#pragma unroll
  for (int ms = 0; ms < 4; ms++) {
#pragma unroll
    for (int reg = 0; reg < 4; reg++) {
      int slot = m0 + wm * 64 + ms * 16 + quad * 4 + reg;
      if (slot < cnt) {
        unsigned short* ar = act + (size_t)(off_e + slot) * FDIM + f0 + wn * 32;
#pragma unroll
        for (int ns = 0; ns < 2; ns++) {
          float h = acc1[ms][ns][reg];
          float g = acc3[ms][ns][reg];
          float a = h / (1.f + __expf(-h)) * g;
          ar[ns * 16 + lrow] = f2bf(a);
        }
      }
    }
  }
}

// ---------------- GEMM2: partial[sk] = act w2^T over K-slice, 128x128 tile ----------------
// A (bf16 act): glds16. B (fp32 w2): distance-2 pipeline, counted-vmcnt barrier.
#define G2_BM 128
#define G2_BN 128
#define SPLITK 2
#define G2_KS (FDIM / SPLITK)   // 1792

__global__ __launch_bounds__(256, 3)
void gemm2_kernel(const unsigned short* __restrict__ act,
                  const float* __restrict__ w2,
                  const int* __restrict__ count,
                  const int* __restrict__ offs,
                  float* __restrict__ part) {
  int zz = blockIdx.z;
  int e = zz & 7, sk = zz >> 3;
  int cnt = count[e];
  int m0 = blockIdx.y * G2_BM;
  if (m0 >= cnt) return;
  int h0 = blockIdx.x * G2_BN;
  int off_e = offs[e];
  int kb = sk * G2_KS;

  __shared__ __align__(16) unsigned short sA[2 * G2_BM * 32];  // 2 x 8 KB
  __shared__ __align__(16) unsigned short sB[2 * G2_BN * 32];  // 2 x 8 KB

  int tid = threadIdx.x;
  int lane = tid & 63, wv = tid >> 6;

  const unsigned short* ag[2];
  char* alb[2];
#pragma unroll
  for (int p = 0; p < 2; p++) {
    int c = tid + p * 256;
    int row = c >> 2, slot = c & 3;
    int gch = slot ^ ((row >> 1) & 3);
    int r = m0 + row;
    int rr = (r < cnt ? r : 0);
    ag[p] = act + (size_t)(off_e + rr) * FDIM + kb + gch * 8;
    alb[p] = (char*)sA + (wv * 64 + p * 256) * 16;
  }
  const float* bg[2];
  unsigned short* bl[2];
#pragma unroll
  for (int p = 0; p < 2; p++) {
    int c = tid + p * 256;
    int row = c >> 2, slot = c & 3;
    int gch = slot ^ ((row >> 1) & 3);
    bg[p] = w2 + ((size_t)e * HDIM + h0 + row) * FDIM + kb + gch * 8;
    bl[p] = sB + c * 8;
  }

  int lrow = lane & 15, quad = lane >> 4;
  int wm = wv >> 1, wn = wv & 1;

  floatx4 acc[4][4];
#pragma unroll
  for (int i = 0; i < 4; i++)
#pragma unroll
    for (int j = 0; j < 4; j++) acc[i][j] = (floatx4){0.f, 0.f, 0.f, 0.f};

  const int NT = G2_KS / BK;  // 56

  // prologue: stage tile 0 + preload B(1)
#pragma unroll
  for (int p = 0; p < 2; p++) glds16(ag[p], alb[p]);
  asm volatile("" ::: "memory");
#pragma unroll
  for (int p = 0; p < 2; p++) {
    float4 a0 = *(const float4*)(bg[p]);
    float4 a1 = *(const float4*)(bg[p] + 4);
    *(short8*)(bl[p]) = pack_bf16(a0, a1);
  }
  float4 cu0[2], cu1[2];
#pragma unroll
  for (int p = 0; p < 2; p++) {
    cu0[p] = *(const float4*)(bg[p] + BK);
    cu1[p] = *(const float4*)(bg[p] + BK + 4);
  }
  PIPE_BARRIER();

  int cur = 0;
  for (int t = 0; t < NT; t++) {
    int nb = cur ^ 1;
#pragma unroll
    for (int p = 0; p < 2; p++)
      *(short8*)(bl[p] + nb * (G2_BN * 32)) = pack_bf16(cu0[p], cu1[p]);
    int k1 = (t + 1 < NT) ? (t + 1) * BK : 0;
#pragma unroll
    for (int p = 0; p < 2; p++) glds16(ag[p] + k1, alb[p] + nb * 8192);
    asm volatile("" ::: "memory");
    int k2 = (t + 2 < NT) ? (t + 2) * BK : 0;
    float4 nu0[2], nu1[2];
#pragma unroll
    for (int p = 0; p < 2; p++) {
      nu0[p] = *(const float4*)(bg[p] + k2);
      nu1[p] = *(const float4*)(bg[p] + k2 + 4);
    }

    const unsigned short* sAc = sA + cur * (G2_BM * 32);
    const unsigned short* sBc = sB + cur * (G2_BN * 32);

    short8 af[4], bf[4];
#pragma unroll
    for (int ms = 0; ms < 4; ms++) {
      int r = wm * 64 + ms * 16 + lrow;
      int sl = quad ^ ((r >> 1) & 3);
      af[ms] = *(const short8*)(sAc + r * 32 + sl * 8);
    }
#pragma unroll
    for (int ns = 0; ns < 4; ns++) {
      int r = wn * 64 + ns * 16 + lrow;
      int sl = quad ^ ((r >> 1) & 3);
      bf[ns] = *(const short8*)(sBc + r * 32 + sl * 8);
    }
#pragma unroll
    for (int ms = 0; ms < 4; ms++)
#pragma unroll
      for (int ns = 0; ns < 4; ns++)
        acc[ms][ns] = __builtin_amdgcn_mfma_f32_16x16x32_bf16(af[ms], bf[ns], acc[ms][ns], 0, 0, 0);

#pragma unroll
    for (int p = 0; p < 2; p++) { cu0[p] = nu0[p]; cu1[p] = nu1[p]; }
    PIPE_BARRIER();
    cur = nb;
  }

#pragma unroll
  for (int ms = 0; ms < 4; ms++) {
#pragma unroll
    for (int reg = 0; reg < 4; reg++) {
      int slot = m0 + wm * 64 + ms * 16 + quad * 4 + reg;
      if (slot < cnt) {
        float* crow = part + ((size_t)sk * 4096 + off_e + slot) * HDIM + h0 + wn * 64;
#pragma unroll
        for (int ns = 0; ns < 4; ns++)
          crow[ns * 16 + lrow] = acc[ms][ns][reg];
      }
    }
  }
}

// ---------------- combine: out[t] = sum_k w_k * sum_sk part[sk][g_k] ----------------
__global__ void combine_kernel(const float* __restrict__ part,
                               const int* __restrict__ slot_of,
                               const float* __restrict__ top_w,
                               float* __restrict__ out) {
  int t = blockIdx.x;
  int g0 = slot_of[t * 2], g1 = slot_of[t * 2 + 1];
  float w0 = top_w[t * 2], w1 = top_w[t * 2 + 1];
  int i = threadIdx.x;   // 256 threads x float4 = 1024 floats
  float4 s0 = {0.f, 0.f, 0.f, 0.f}, s1 = {0.f, 0.f, 0.f, 0.f};
#pragma unroll
  for (int sk = 0; sk < SPLITK; sk++) {
    float4 a = ((const float4*)(part + ((size_t)sk * 4096 + g0) * HDIM))[i];
    float4 b = ((const float4*)(part + ((size_t)sk * 4096 + g1) * HDIM))[i];
    s0.x += a.x; s0.y += a.y; s0.z += a.z; s0.w += a.w;
    s1.x += b.x; s1.y += b.y; s1.z += b.z; s1.w += b.w;
  }
  float4 r;
  r.x = w0 * s0.x + w1 * s1.x;
  r.y = w0 * s0.y + w1 * s1.y;
  r.z = w0 * s0.z + w1 * s1.z;
  r.w = w0 * s0.w + w1 * s1.w;
  ((float4*)(out + (size_t)t * HDIM))[i] = r;
}

// ---------------- launcher ----------------
extern "C" void kernel_launch(void* const* d_in, const int* in_sizes, int n_in,
                              void* d_out, int out_size, void* d_ws, size_t ws_size,
                              hipStream_t stream) {
  const float* x  = (const float*)d_in[0];
  const float* gw = (const float*)d_in[1];
  const float* w1 = (const float*)d_in[2];
  const float* w3 = (const float*)d_in[3];
  const float* w2 = (const float*)d_in[4];
  float* out = (float*)d_out;

  char* ws = (char*)d_ws;
  const size_t MB = 1ull << 20;
  // layout (~67 MB total):
  //   [0,1)    small buffers
  //   [1,5)    xbf (4 MB)
  //   [5,35)   act  (28 MB used)
  //   [35,67)  part (32 MB, SPLITK=2)
  float* top_w = (float*)(ws);
  int* top_e   = (int*)(ws + 16384);
  int* slot_of = (int*)(ws + 32768);
  int* tok_of  = (int*)(ws + 49152);
  int* count   = (int*)(ws + 65536);
  int* offs    = (int*)(ws + 65536 + 64);

  unsigned short* xbf = (unsigned short*)(ws + 1 * MB);
  unsigned short* act = (unsigned short*)(ws + 5 * MB);
  float* part = (float*)(ws + 35 * MB);

  gate_kernel<<<TOKENS / 4, 256, 0, stream>>>(x, gw, xbf, top_e, top_w);
  route_kernel<<<1, 1024, 0, stream>>>(top_e, count, offs, tok_of, slot_of);
  gemm1_kernel<<<dim3(FDIM / G1_BF, TOKENS / G1_BM, NEXP), 256, 0, stream>>>(
      xbf, w1, w3, count, offs, tok_of, act);
  gemm2_kernel<<<dim3(HDIM / G2_BN, TOKENS / G2_BM, NEXP * SPLITK), 256, 0, stream>>>(
      act, w2, count, offs, part);
  combine_kernel<<<TOKENS, 256, 0, stream>>>(part, slot_of, top_w, out);
}